// Round 2
// baseline (15454.678 us; speedup 1.0000x reference)
//
#include <hip/hip_runtime.h>

// Recurrent MLP emulator: B=65536 rows, T=256 steps, MLP 18->32->32->14 with
// residual latent update. One thread per batch row. ALL state hand-expanded
// into named scalar registers (no arrays -> no scratch). Weights are
// wave-uniform scalar loads (SGPR broadcast, L2-resident).

#define BB 65536
#define TT 256
#define PP 4
#define LL 14
#define HH 32

#define REP14(M) M(0) M(1) M(2) M(3) M(4) M(5) M(6) M(7) M(8) M(9) M(10) M(11) M(12) M(13)
#define REP32(M) M(0) M(1) M(2) M(3) M(4) M(5) M(6) M(7) M(8) M(9) M(10) M(11) M(12) M(13) M(14) M(15) \
                 M(16) M(17) M(18) M(19) M(20) M(21) M(22) M(23) M(24) M(25) M(26) M(27) M(28) M(29) M(30) M(31)
// 32-term accumulator expansion: ACC32(M, j) -> M(0,j) M(1,j) ... M(31,j)
#define ACC32(M, j) M(0,j) M(1,j) M(2,j) M(3,j) M(4,j) M(5,j) M(6,j) M(7,j) \
                    M(8,j) M(9,j) M(10,j) M(11,j) M(12,j) M(13,j) M(14,j) M(15,j) \
                    M(16,j) M(17,j) M(18,j) M(19,j) M(20,j) M(21,j) M(22,j) M(23,j) \
                    M(24,j) M(25,j) M(26,j) M(27,j) M(28,j) M(29,j) M(30,j) M(31,j)

__global__ __launch_bounds__(256, 1)
void emulator_kernel(const float* __restrict__ phys,
                     const float* __restrict__ latents,
                     const float* __restrict__ W1,
                     const float* __restrict__ b1,
                     const float* __restrict__ W2,
                     const float* __restrict__ b2,
                     const float* __restrict__ W3,
                     const float* __restrict__ b3,
                     float* __restrict__ out) {
    const int b = blockIdx.x * blockDim.x + threadIdx.x;

    // Latent state: 14 named scalar registers.
#define DECL_LAT(i) float lat##i = latents[(size_t)b * LL + (i)];
    REP14(DECL_LAT)
#undef DECL_LAT

    // phys[b][t][0:4] is a 16B-aligned float4 per (b,t).
    const float4* __restrict__ physv =
        reinterpret_cast<const float4*>(phys + (size_t)b * TT * PP);
    float4 ph = physv[0];

    float* __restrict__ outp = out + (size_t)b * TT * LL;

#pragma unroll 1
    for (int t = 0; t < TT; ++t) {
        const float4 ph_next = physv[(t < TT - 1) ? (t + 1) : t];

        // ---- layer 1: h1_j = relu(b1[j] + x . W1[:,j]),  x = [ph, lat] ----
#define L1(j) float h1_##j; { \
        float a = fmaf(ph.x, W1[0*HH+(j)], b1[(j)]); \
        a = fmaf(ph.y,  W1[ 1*HH+(j)], a); \
        a = fmaf(ph.z,  W1[ 2*HH+(j)], a); \
        a = fmaf(ph.w,  W1[ 3*HH+(j)], a); \
        a = fmaf(lat0,  W1[ 4*HH+(j)], a); \
        a = fmaf(lat1,  W1[ 5*HH+(j)], a); \
        a = fmaf(lat2,  W1[ 6*HH+(j)], a); \
        a = fmaf(lat3,  W1[ 7*HH+(j)], a); \
        a = fmaf(lat4,  W1[ 8*HH+(j)], a); \
        a = fmaf(lat5,  W1[ 9*HH+(j)], a); \
        a = fmaf(lat6,  W1[10*HH+(j)], a); \
        a = fmaf(lat7,  W1[11*HH+(j)], a); \
        a = fmaf(lat8,  W1[12*HH+(j)], a); \
        a = fmaf(lat9,  W1[13*HH+(j)], a); \
        a = fmaf(lat10, W1[14*HH+(j)], a); \
        a = fmaf(lat11, W1[15*HH+(j)], a); \
        a = fmaf(lat12, W1[16*HH+(j)], a); \
        a = fmaf(lat13, W1[17*HH+(j)], a); \
        h1_##j = fmaxf(a, 0.0f); }
        REP32(L1)
#undef L1

        // ---- layer 2: h2_j = relu(b2[j] + h1 . W2[:,j]) ----
#define L2T(k, j) a = fmaf(h1_##k, W2[(k)*HH+(j)], a);
#define L2(j) float h2_##j; { \
        float a = b2[(j)]; \
        ACC32(L2T, j) \
        h2_##j = fmaxf(a, 0.0f); }
        REP32(L2)
#undef L2
#undef L2T

        // ---- layer 3 + residual: lat_l += b3[l] + h2 . W3[:,l] ----
#define L3T(k, l) a = fmaf(h2_##k, W3[(k)*LL+(l)], a);
#define L3(l) { \
        float a = b3[(l)]; \
        ACC32(L3T, l) \
        lat##l += a; }
        REP14(L3)
#undef L3
#undef L3T

        // ---- store out[b][t][:]: 14 floats, 8B-aligned -> 7 x float2 ----
        float2* __restrict__ o2 = reinterpret_cast<float2*>(outp + t * LL);
        o2[0] = make_float2(lat0,  lat1);
        o2[1] = make_float2(lat2,  lat3);
        o2[2] = make_float2(lat4,  lat5);
        o2[3] = make_float2(lat6,  lat7);
        o2[4] = make_float2(lat8,  lat9);
        o2[5] = make_float2(lat10, lat11);
        o2[6] = make_float2(lat12, lat13);

        ph = ph_next;
    }
}

extern "C" void kernel_launch(void* const* d_in, const int* in_sizes, int n_in,
                              void* d_out, int out_size, void* d_ws, size_t ws_size,
                              hipStream_t stream) {
    const float* phys    = (const float*)d_in[0];
    const float* latents = (const float*)d_in[1];
    const float* W1      = (const float*)d_in[2];
    const float* b1      = (const float*)d_in[3];
    const float* W2      = (const float*)d_in[4];
    const float* b2      = (const float*)d_in[5];
    const float* W3      = (const float*)d_in[6];
    const float* b3      = (const float*)d_in[7];
    float* out = (float*)d_out;

    const int threads = 256;
    const int blocks = BB / threads;  // 256 blocks, 1 per CU
    emulator_kernel<<<blocks, threads, 0, stream>>>(
        phys, latents, W1, b1, W2, b2, W3, b3, out);
}

// Round 4
// 1962.495 us; speedup vs baseline: 7.8750x; 7.8750x over previous
//
#include <hip/hip_runtime.h>

// Recurrent MLP emulator: B=65536 rows, T=256 steps, MLP 18->32->32->14 with
// residual latent update. One thread per batch row; state in registers.
// KEY: weights are read through the CONSTANT address space (addrspace(4)),
// forcing s_load_dwordxN into SGPRs -> v_fma_f32 v,s,v consumes them with no
// per-lane replication (no LDS, no VGPR waste). An empty asm barrier stops
// LICM from hoisting 8.5KB of weights out of the t-loop (they re-stream
// through the scalar cache every step, overlapped with VALU on the FMA pipe).

#define BB 65536
#define TT 256
#define PP 4
#define LL 14
#define HH 32
#define INW 18

typedef const __attribute__((address_space(4))) float* cfp;

__global__ __launch_bounds__(256, 1)
void emulator_kernel(const float* __restrict__ phys,
                     const float* __restrict__ latents,
                     const float* __restrict__ W1g,
                     const float* __restrict__ b1g,
                     const float* __restrict__ W2g,
                     const float* __restrict__ b2g,
                     const float* __restrict__ W3g,
                     const float* __restrict__ b3g,
                     float* __restrict__ out) {
    const int tid = threadIdx.x;
    const int b = blockIdx.x * blockDim.x + tid;

    // Weight pointers as integers; the asm barrier in the loop "modifies"
    // them each iteration so weight loads cannot be hoisted or CSE'd across t.
    unsigned long long aW1 = (unsigned long long)W1g;
    unsigned long long ab1 = (unsigned long long)b1g;
    unsigned long long aW2 = (unsigned long long)W2g;
    unsigned long long ab2 = (unsigned long long)b2g;
    unsigned long long aW3 = (unsigned long long)W3g;
    unsigned long long ab3 = (unsigned long long)b3g;

    // Latent state in registers (float2 vector loads; 56B row stride is 8B-aligned).
    float lat[LL];
    {
        const float2* l2 = reinterpret_cast<const float2*>(latents + (size_t)b * LL);
#pragma unroll
        for (int i = 0; i < LL / 2; ++i) {
            const float2 v = l2[i];
            lat[2 * i] = v.x;
            lat[2 * i + 1] = v.y;
        }
    }

    // phys[b][t][0:4] is a 16B-aligned float4 per (b,t).
    const float4* __restrict__ physv =
        reinterpret_cast<const float4*>(phys + (size_t)b * TT * PP);
    float4 ph = physv[0];

    float* __restrict__ outp = out + (size_t)b * TT * LL;

#pragma unroll 1
    for (int t = 0; t < TT; ++t) {
        // Anti-LICM: pretend the weight bases change every iteration.
        asm volatile("" : "+s"(aW1), "+s"(ab1), "+s"(aW2), "+s"(ab2), "+s"(aW3), "+s"(ab3));
        const cfp W1 = (cfp)aW1;
        const cfp b1 = (cfp)ab1;
        const cfp W2 = (cfp)aW2;
        const cfp b2 = (cfp)ab2;
        const cfp W3 = (cfp)aW3;
        const cfp b3 = (cfp)ab3;

        const float4 ph_next = physv[(t < TT - 1) ? (t + 1) : t];

        // Input vector x = [ph, lat] (SROA -> registers, constant indices).
        float x[INW];
        x[0] = ph.x; x[1] = ph.y; x[2] = ph.z; x[3] = ph.w;
#pragma unroll
        for (int i = 0; i < LL; ++i) x[PP + i] = lat[i];

        // ---- layer 1: h1 = relu(b1 + x @ W1) ----
        float h1[HH];
#pragma unroll
        for (int j = 0; j < HH; ++j) h1[j] = b1[j];
#pragma unroll
        for (int i = 0; i < INW; ++i) {
            const float xi = x[i];
#pragma unroll
            for (int j = 0; j < HH; ++j) h1[j] = fmaf(xi, W1[i * HH + j], h1[j]);
        }
#pragma unroll
        for (int j = 0; j < HH; ++j) h1[j] = fmaxf(h1[j], 0.0f);

        // ---- layer 2: h2 = relu(b2 + h1 @ W2) ----
        float h2[HH];
#pragma unroll
        for (int j = 0; j < HH; ++j) h2[j] = b2[j];
#pragma unroll
        for (int k = 0; k < HH; ++k) {
            const float hk = h1[k];
#pragma unroll
            for (int j = 0; j < HH; ++j) h2[j] = fmaf(hk, W2[k * HH + j], h2[j]);
        }
#pragma unroll
        for (int j = 0; j < HH; ++j) h2[j] = fmaxf(h2[j], 0.0f);

        // ---- layer 3 + residual: lat += b3 + h2 @ W3 ----
#pragma unroll
        for (int l = 0; l < LL; ++l) lat[l] += b3[l];
#pragma unroll
        for (int k = 0; k < HH; ++k) {
            const float hk = h2[k];
#pragma unroll
            for (int l = 0; l < LL; ++l) lat[l] = fmaf(hk, W3[k * LL + l], lat[l]);
        }

        // ---- store out[b][t][:]: 14 floats, 8B-aligned -> 7 x float2 ----
        float2* __restrict__ o2 = reinterpret_cast<float2*>(outp + t * LL);
#pragma unroll
        for (int l = 0; l < LL / 2; ++l)
            o2[l] = make_float2(lat[2 * l], lat[2 * l + 1]);

        ph = ph_next;
    }
}

extern "C" void kernel_launch(void* const* d_in, const int* in_sizes, int n_in,
                              void* d_out, int out_size, void* d_ws, size_t ws_size,
                              hipStream_t stream) {
    const float* phys    = (const float*)d_in[0];
    const float* latents = (const float*)d_in[1];
    const float* W1      = (const float*)d_in[2];
    const float* b1      = (const float*)d_in[3];
    const float* W2      = (const float*)d_in[4];
    const float* b2      = (const float*)d_in[5];
    const float* W3      = (const float*)d_in[6];
    const float* b3      = (const float*)d_in[7];
    float* out = (float*)d_out;

    const int threads = 256;
    const int blocks = BB / threads;  // 256 blocks, 1 per CU
    emulator_kernel<<<blocks, threads, 0, stream>>>(
        phys, latents, W1, b1, W2, b2, W3, b3, out);
}

// Round 5
// 1906.322 us; speedup vs baseline: 8.1071x; 1.0295x over previous
//
#include <hip/hip_runtime.h>

// Recurrent MLP emulator: B=65536 rows, T=256 steps, MLP 18->32->32->14.
// One thread per row; weights via constant-addrspace scalar loads (SGPR
// broadcast). Dataflow restructured so peak register liveness is ~58 floats:
//   L1 h1 produced in groups of 4 (dot-18 each), ReLU'd, immediately
//   consumed into the 32 L2 accumulators, then dead.
//   L2 accumulators consumed one-at-a-time (ReLU + 14 FMAs into lat) in L3.
// This removes the 78-float live plateau that forced the R4 compiler into
// rematerialization (4.1K VALU instrs/step instead of 2.1K).

#define BB 65536
#define TT 256
#define PP 4
#define LL 14
#define HH 32
#define INW 18

typedef const __attribute__((address_space(4))) float* cfp;

__global__ __launch_bounds__(256, 1)
void emulator_kernel(const float* __restrict__ phys,
                     const float* __restrict__ latents,
                     const float* __restrict__ W1g,
                     const float* __restrict__ b1g,
                     const float* __restrict__ W2g,
                     const float* __restrict__ b2g,
                     const float* __restrict__ W3g,
                     const float* __restrict__ b3g,
                     float* __restrict__ out) {
    const int tid = threadIdx.x;
    const int b = blockIdx.x * blockDim.x + tid;

    // Weight pointers as integers; the asm barrier in the loop "modifies"
    // them each iteration so 8.5KB of weights can't be hoisted out (LICM)
    // into nonexistent SGPR space. They re-stream through the scalar cache.
    unsigned long long aW1 = (unsigned long long)W1g;
    unsigned long long ab1 = (unsigned long long)b1g;
    unsigned long long aW2 = (unsigned long long)W2g;
    unsigned long long ab2 = (unsigned long long)b2g;
    unsigned long long aW3 = (unsigned long long)W3g;
    unsigned long long ab3 = (unsigned long long)b3g;

    // Latent state in registers.
    float lat[LL];
    {
        const float2* l2 = reinterpret_cast<const float2*>(latents + (size_t)b * LL);
#pragma unroll
        for (int i = 0; i < LL / 2; ++i) {
            const float2 v = l2[i];
            lat[2 * i] = v.x;
            lat[2 * i + 1] = v.y;
        }
    }

    // phys[b][t][0:4] is a 16B-aligned float4 per (b,t).
    const float4* __restrict__ physv =
        reinterpret_cast<const float4*>(phys + (size_t)b * TT * PP);
    float4 ph = physv[0];

    float* __restrict__ outp = out + (size_t)b * TT * LL;

#pragma unroll 1
    for (int t = 0; t < TT; ++t) {
        asm volatile("" : "+s"(aW1), "+s"(ab1), "+s"(aW2), "+s"(ab2), "+s"(aW3), "+s"(ab3));
        const cfp W1 = (cfp)aW1;
        const cfp B1 = (cfp)ab1;
        const cfp W2 = (cfp)aW2;
        const cfp B2 = (cfp)ab2;
        const cfp W3 = (cfp)aW3;
        const cfp B3 = (cfp)ab3;

        const float4 ph_next = physv[(t < TT - 1) ? (t + 1) : t];

        // ---- L2 accumulators, initialized with b2 ----
        float acc2[HH];
#pragma unroll
        for (int j = 0; j < HH; ++j) acc2[j] = B2[j];

        // ---- L1 fused into L2: produce h1 in groups of 4, consume, kill ----
#pragma unroll
        for (int g = 0; g < HH / 4; ++g) {
            float hg0 = B1[4 * g + 0];
            float hg1 = B1[4 * g + 1];
            float hg2 = B1[4 * g + 2];
            float hg3 = B1[4 * g + 3];
            // W1[i][4g .. 4g+3] is a contiguous 16B run -> s_load_dwordx4.
#define ACC4(xi, i) { const float xv = (xi); \
            hg0 = fmaf(xv, W1[(i) * HH + 4 * g + 0], hg0); \
            hg1 = fmaf(xv, W1[(i) * HH + 4 * g + 1], hg1); \
            hg2 = fmaf(xv, W1[(i) * HH + 4 * g + 2], hg2); \
            hg3 = fmaf(xv, W1[(i) * HH + 4 * g + 3], hg3); }
            ACC4(ph.x, 0)
            ACC4(ph.y, 1)
            ACC4(ph.z, 2)
            ACC4(ph.w, 3)
#pragma unroll
            for (int i = 0; i < LL; ++i) { ACC4(lat[i], 4 + i) }
#undef ACC4
            hg0 = fmaxf(hg0, 0.0f);
            hg1 = fmaxf(hg1, 0.0f);
            hg2 = fmaxf(hg2, 0.0f);
            hg3 = fmaxf(hg3, 0.0f);
            // Consume into all 32 L2 accumulators; hg* die here.
#pragma unroll
            for (int j = 0; j < HH; ++j)
                acc2[j] = fmaf(hg0, W2[(4 * g + 0) * HH + j], acc2[j]);
#pragma unroll
            for (int j = 0; j < HH; ++j)
                acc2[j] = fmaf(hg1, W2[(4 * g + 1) * HH + j], acc2[j]);
#pragma unroll
            for (int j = 0; j < HH; ++j)
                acc2[j] = fmaf(hg2, W2[(4 * g + 2) * HH + j], acc2[j]);
#pragma unroll
            for (int j = 0; j < HH; ++j)
                acc2[j] = fmaf(hg3, W2[(4 * g + 3) * HH + j], acc2[j]);
        }

        // ---- L3 fused: consume acc2[k] one at a time into lat ----
#pragma unroll
        for (int l = 0; l < LL; ++l) lat[l] += B3[l];
#pragma unroll
        for (int k = 0; k < HH; ++k) {
            const float hk = fmaxf(acc2[k], 0.0f);
#pragma unroll
            for (int l = 0; l < LL; ++l)
                lat[l] = fmaf(hk, W3[k * LL + l], lat[l]);
        }

        // ---- store out[b][t][:]: 14 floats, 8B-aligned -> 7 x float2 ----
        float2* __restrict__ o2 = reinterpret_cast<float2*>(outp + t * LL);
#pragma unroll
        for (int l = 0; l < LL / 2; ++l)
            o2[l] = make_float2(lat[2 * l], lat[2 * l + 1]);

        ph = ph_next;
    }
}

extern "C" void kernel_launch(void* const* d_in, const int* in_sizes, int n_in,
                              void* d_out, int out_size, void* d_ws, size_t ws_size,
                              hipStream_t stream) {
    const float* phys    = (const float*)d_in[0];
    const float* latents = (const float*)d_in[1];
    const float* W1      = (const float*)d_in[2];
    const float* b1      = (const float*)d_in[3];
    const float* W2      = (const float*)d_in[4];
    const float* b2      = (const float*)d_in[5];
    const float* W3      = (const float*)d_in[6];
    const float* b3      = (const float*)d_in[7];
    float* out = (float*)d_out;

    const int threads = 256;
    const int blocks = BB / threads;  // 256 blocks, 1 per CU
    emulator_kernel<<<blocks, threads, 0, stream>>>(
        phys, latents, W1, b1, W2, b2, W3, b3, out);
}